// Round 4
// baseline (127.766 us; speedup 1.0000x reference)
//
#include <hip/hip_runtime.h>
#include <math.h>

#define BB 16
#define SS 8192
#define HH 256
#define MM 16
#define NV 2049          // folded v range: 0..2048
#define DNC 65           // k_dft partial chunks: 64 waves + 1 edge (v=2048)
#define SCH 16           // v per k_synth block
#define SNC 129          // k_synth chunks: 128 full + 1 edge

// ws layout (floats): T [NV][32] at 0 (reserve 262144), AB at 262144,
// Xs at 393216.  d_out scratch: Xp [BB][DNC][MM][2][HH] (8.5M floats) at 0,
// Wt_r at 16M floats, Wt_i at 17M floats — all consumed before k_synth writes.

__global__ __launch_bounds__(256) void k_twiddle(float* __restrict__ T) {
    int idx = blockIdx.x * 256 + threadIdx.x;   // 0 .. NV*MM-1
    if (idx >= NV * MM) return;
    int v = idx >> 4, k = idx & 15;
    int r = (k * v) & (SS - 1);                 // exact angle reduction
    float th = (float)r * (6.28318530717958647692f / (float)SS);
    float sn, cn;
    sincosf(th, &sn, &cn);
    T[v * 32 + 2 * k]     = cn;
    T[v * 32 + 2 * k + 1] = sn;
}

// Transpose W: Wt[m][h][k'] = w[h][k'][m].
__global__ __launch_bounds__(256) void k_wt(const float* __restrict__ wr,
                                            const float* __restrict__ wi,
                                            float* __restrict__ Wtr,
                                            float* __restrict__ Wti) {
    __shared__ float lds[4096 + 256];
    const int h = blockIdx.x, t = threadIdx.x;
    const float* src = (blockIdx.y == 0 ? wr : wi) + (size_t)h * 4096;
    float* dst = (blockIdx.y == 0 ? Wtr : Wti);
#pragma unroll
    for (int j = 0; j < 16; j++) {
        int i = j * 256 + t;
        lds[i + (i >> 4)] = src[i];
    }
    __syncthreads();
#pragma unroll
    for (int m = 0; m < 16; m++) {
        int i = t * 16 + m;
        dst[(size_t)m * (HH * HH) + (size_t)h * HH + t] = lds[i + (i >> 4)];
    }
}

// Branchless exact-GELU via A&S 7.1.26 erf (|err| ~ 1.5e-7).
__device__ __forceinline__ float fast_gelu(float y) {
    float x  = fabsf(y) * 0.70710678118654752f;
    float t  = __builtin_amdgcn_rcpf(fmaf(0.3275911f, x, 1.0f));
    float e  = __expf(-x * x);
    float p  = fmaf(fmaf(fmaf(fmaf(1.061405429f, t, -1.453152027f), t,
                   1.421413741f), t, -0.284496736f), t, 0.254829592f) * t;
    float erfabs = fmaf(-p, e, 1.0f);
    return fmaf(0.5f * fabsf(y), erfabs, 0.5f * y);
}

// Stage 1: folded pruned DFT, float4 along h, one partial chunk per WAVE.
// Rows {v, 8192-v, 4096-v, 4096+v}:
//   even k: cs += c*(u+w), sn += s*(d+e); odd k: cs += c*(u-w), sn += s*(d-e)
// v in {0,2048}: duplicate rows -> weight 0.5 (exact, verified R3).
// Grid (17, BB): blocks 0..15 = 4 waves x 32 v; block 16 = edge v=2048.
__global__ __launch_bounds__(256) void k_dft(const float* __restrict__ x,
                                             const float* __restrict__ T,
                                             float* __restrict__ Xp) {
    const int b = blockIdx.y;
    const int wave = threadIdx.x >> 6, lane = threadIdx.x & 63;
    const int h4 = lane << 2;
    const float* xb = x + (size_t)b * SS * HH + h4;

    float cs[MM][4], sn[MM][4];
#pragma unroll
    for (int k = 0; k < MM; k++)
#pragma unroll
        for (int c = 0; c < 4; c++) { cs[k][c] = 0.f; sn[k][c] = 0.f; }

    auto body = [&](int v) {
        float hf = (v == 0 || v == SS / 4) ? 0.5f : 1.0f;
        float4 a0 = *(const float4*)(xb + (size_t)v * HH);
        float4 a1 = *(const float4*)(xb + (size_t)((SS - v) & (SS - 1)) * HH);
        float4 a2 = *(const float4*)(xb + (size_t)(SS / 2 - v) * HH);
        float4 a3 = *(const float4*)(xb + (size_t)(SS / 2 + v) * HH);
        const float* p0 = (const float*)&a0;
        const float* p1 = (const float*)&a1;
        const float* p2 = (const float*)&a2;
        const float* p3 = (const float*)&a3;
        float upw[4], umw[4], dpe[4], dme[4];
#pragma unroll
        for (int c = 0; c < 4; c++) {
            float u = (p0[c] + p1[c]) * hf, d = (p0[c] - p1[c]) * hf;
            float w = (p2[c] + p3[c]) * hf, e = (p3[c] - p2[c]) * hf;
            upw[c] = u + w; umw[c] = u - w; dpe[c] = d + e; dme[c] = d - e;
        }
        const float4* tw4 = (const float4*)(T + (size_t)v * 32);
#pragma unroll
        for (int j = 0; j < 8; j++) {
            float4 t = tw4[j];
#pragma unroll
            for (int c = 0; c < 4; c++) {
                cs[2 * j][c]     = fmaf(t.x, upw[c], cs[2 * j][c]);
                sn[2 * j][c]     = fmaf(t.y, dpe[c], sn[2 * j][c]);
                cs[2 * j + 1][c] = fmaf(t.z, umw[c], cs[2 * j + 1][c]);
                sn[2 * j + 1][c] = fmaf(t.w, dme[c], sn[2 * j + 1][c]);
            }
        }
    };

    int wchunk;
    if (blockIdx.x < 16) {
        wchunk = blockIdx.x * 4 + wave;        // 0..63
        const int v0 = wchunk * 32;
#pragma unroll 2
        for (int i = 0; i < 32; i++) body(v0 + i);
    } else {
        if (wave != 0) return;
        wchunk = 64;
        body(SS / 4);                          // v = 2048
    }

    size_t base = ((size_t)(b * DNC + wchunk) * MM) * (2 * HH) + h4;
#pragma unroll
    for (int k = 0; k < MM; k++) {
        *(float4*)(Xp + base + (size_t)k * (2 * HH)) =
            make_float4(cs[k][0], cs[k][1], cs[k][2], cs[k][3]);
        *(float4*)(Xp + base + (size_t)k * (2 * HH) + HH) =
            make_float4(sn[k][0], sn[k][1], sn[k][2], sn[k][3]);
    }
}

// Stage 2a: reduce partials over chunks.
__global__ __launch_bounds__(256) void k_reduce(const float* __restrict__ Xp,
                                                float* __restrict__ Xs) {
    const int t = blockIdx.x * 256 + threadIdx.x;
    const int INNER = MM * 2 * HH;                  // 8192
    int idx4 = t * 4;
    int inner = idx4 & (INNER - 1);
    int b = idx4 >> 13;
    const float* src = Xp + ((size_t)b * DNC) * INNER + inner;
    float4 s = make_float4(0.f, 0.f, 0.f, 0.f);
#pragma unroll 5
    for (int p = 0; p < DNC; p++) {
        float4 v = *(const float4*)(src + (size_t)p * INNER);
        s.x += v.x; s.y += v.y; s.z += v.z; s.w += v.w;
    }
    *(float4*)(Xs + idx4) = s;
}

// Stage 2b: complex mix.
__global__ __launch_bounds__(256) void k_mix2(const float* __restrict__ Xs,
                                              const float* __restrict__ Wtr,
                                              const float* __restrict__ Wti,
                                              float* __restrict__ AB) {
    const int m = blockIdx.x, b = blockIdx.y, t = threadIdx.x;
    __shared__ float xr_s[HH], xs_s[HH];
    size_t xbase = (((size_t)b * MM + m) * 2) * HH;
    xr_s[t] = Xs[xbase + t];
    xs_s[t] = Xs[xbase + HH + t];
    __syncthreads();

    const float* wr_m = Wtr + (size_t)m * (HH * HH);
    const float* wi_m = Wti + (size_t)m * (HH * HH);
    float re = 0.f, im = 0.f;
#pragma unroll 8
    for (int h = 0; h < HH; h++) {
        float a  = wr_m[(size_t)h * HH + t];
        float bw = wi_m[(size_t)h * HH + t];
        float xr = xr_s[h];
        float xs = xs_s[h];
        re = fmaf(xr, a, re);  re = fmaf(xs, bw, re);
        im = fmaf(xr, bw, im); im = fmaf(-xs, a, im);
    }
    float scale = (m == 0 ? 1.f : 2.f) / (float)SS;
    size_t o = (((size_t)b * MM + m) * 2) * HH + t;
    AB[o]      = scale * re;
    AB[o + HH] = -scale * im;
}

// Stage 3: folded synthesis + GELU (4 scattered stores per table row).
__global__ __launch_bounds__(256) void k_synth(const float* __restrict__ AB,
                                               const float* __restrict__ T,
                                               float* __restrict__ out) {
    const int c = blockIdx.x, b = blockIdx.y, h = threadIdx.x;
    float a[MM], bc[MM];
#pragma unroll
    for (int k = 0; k < MM; k++) {
        size_t o = (((size_t)b * MM + k) * 2) * HH + h;
        a[k]  = AB[o];
        bc[k] = AB[o + HH];
    }
    const int nv = (c == SNC - 1) ? 1 : SCH;
    const int v0 = c * SCH;
    float* ob = out + (size_t)b * SS * HH + h;

#pragma unroll 2
    for (int i = 0; i < nv; i++) {
        int v = v0 + i;
        const float4* tw4 = (const float4*)(T + (size_t)v * 32);
        float Pe = 0.f, Po = 0.f, Qe = 0.f, Qo = 0.f;
#pragma unroll
        for (int j = 0; j < 8; j++) {
            float4 t = tw4[j];
            Pe = fmaf(a[2 * j],      t.x, Pe);
            Qe = fmaf(bc[2 * j],     t.y, Qe);
            Po = fmaf(a[2 * j + 1],  t.z, Po);
            Qo = fmaf(bc[2 * j + 1], t.w, Qo);
        }
        float Pp = Pe + Po, Pm = Pe - Po, Qp = Qe + Qo, Qm = Qe - Qo;
        ob[(size_t)v * HH]                        = fast_gelu(Pp + Qp);
        ob[(size_t)(SS / 2 - v) * HH]             = fast_gelu(Pm - Qm);
        ob[(size_t)(SS / 2 + v) * HH]             = fast_gelu(Pm + Qm);
        ob[(size_t)((SS - v) & (SS - 1)) * HH]    = fast_gelu(Pp - Qp);
    }
}

extern "C" void kernel_launch(void* const* d_in, const int* in_sizes, int n_in,
                              void* d_out, int out_size, void* d_ws, size_t ws_size,
                              hipStream_t stream) {
    const float* x   = (const float*)d_in[0];
    const float* w_r = (const float*)d_in[1];
    const float* w_i = (const float*)d_in[2];
    float* out = (float*)d_out;
    float* ws  = (float*)d_ws;

    float* T   = ws;
    float* AB  = ws + 262144;
    float* Xs  = ws + 393216;
    float* Xp  = out;                             // 8.5M floats scratch
    float* Wtr = out + (size_t)16 * 1024 * 1024;  // 1M floats scratch
    float* Wti = out + (size_t)17 * 1024 * 1024;  // 1M floats scratch

    hipLaunchKernelGGL(k_twiddle, dim3((NV * MM + 255) / 256), dim3(256), 0, stream, T);
    hipLaunchKernelGGL(k_wt,     dim3(HH, 2), dim3(256), 0, stream, w_r, w_i, Wtr, Wti);
    hipLaunchKernelGGL(k_dft,    dim3(17, BB), dim3(256), 0, stream, x, T, Xp);
    hipLaunchKernelGGL(k_reduce, dim3(BB * MM * 2 * HH / 1024), dim3(256), 0, stream, Xp, Xs);
    hipLaunchKernelGGL(k_mix2,   dim3(MM, BB), dim3(256), 0, stream, Xs, Wtr, Wti, AB);
    hipLaunchKernelGGL(k_synth,  dim3(SNC, BB), dim3(256), 0, stream, AB, T, out);
}

// Round 5
// 127.700 us; speedup vs baseline: 1.0005x; 1.0005x over previous
//
#include <hip/hip_runtime.h>
#include <math.h>

#define BB 16
#define SS 8192
#define HH 256
#define MM 16
#define NV 2049          // folded v range: 0..2048
#define DNC 65           // k_dft partial chunks: 64 v-chunks + 1 edge (v=2048)
#define SCH 16           // v per k_synth block
#define SNC 129          // k_synth chunks: 128 full + 1 edge

// ws layout (floats): T [NV][32] at 0 (reserve 262144), AB at 262144,
// Xs at 393216.  d_out scratch: Xp [BB][DNC][MM][2][HH] (8.5M floats) at 0,
// Wt_r at 16M floats, Wt_i at 17M floats — all consumed before k_synth writes.

__global__ __launch_bounds__(256) void k_twiddle(float* __restrict__ T) {
    int idx = blockIdx.x * 256 + threadIdx.x;   // 0 .. NV*MM-1
    if (idx >= NV * MM) return;
    int v = idx >> 4, k = idx & 15;
    int r = (k * v) & (SS - 1);                 // exact angle reduction
    float th = (float)r * (6.28318530717958647692f / (float)SS);
    float sn, cn;
    sincosf(th, &sn, &cn);
    T[v * 32 + 2 * k]     = cn;
    T[v * 32 + 2 * k + 1] = sn;
}

// Transpose W: Wt[m][h][k'] = w[h][k'][m].
__global__ __launch_bounds__(256) void k_wt(const float* __restrict__ wr,
                                            const float* __restrict__ wi,
                                            float* __restrict__ Wtr,
                                            float* __restrict__ Wti) {
    __shared__ float lds[4096 + 256];
    const int h = blockIdx.x, t = threadIdx.x;
    const float* src = (blockIdx.y == 0 ? wr : wi) + (size_t)h * 4096;
    float* dst = (blockIdx.y == 0 ? Wtr : Wti);
#pragma unroll
    for (int j = 0; j < 16; j++) {
        int i = j * 256 + t;
        lds[i + (i >> 4)] = src[i];
    }
    __syncthreads();
#pragma unroll
    for (int m = 0; m < 16; m++) {
        int i = t * 16 + m;
        dst[(size_t)m * (HH * HH) + (size_t)h * HH + t] = lds[i + (i >> 4)];
    }
}

// Branchless exact-GELU via A&S 7.1.26 erf (|err| ~ 1.5e-7).
__device__ __forceinline__ float fast_gelu(float y) {
    float x  = fabsf(y) * 0.70710678118654752f;
    float t  = __builtin_amdgcn_rcpf(fmaf(0.3275911f, x, 1.0f));
    float e  = __expf(-x * x);
    float p  = fmaf(fmaf(fmaf(fmaf(1.061405429f, t, -1.453152027f), t,
                   1.421413741f), t, -0.284496736f), t, 0.254829592f) * t;
    float erfabs = fmaf(-p, e, 1.0f);
    return fmaf(0.5f * fabsf(y), erfabs, 0.5f * y);
}

// Stage 1: folded pruned DFT.  One wave = (v-chunk of 32, h-half of 128),
// float2 along h.  128 wave-jobs per batch -> 2048 waves (8/CU).
// Rows {v, 8192-v, 4096-v, 4096+v}:
//   even k: cs += c*(u+w), sn += s*(d+e); odd k: cs += c*(u-w), sn += s*(d-e)
// v in {0,2048}: duplicate rows -> weight 0.5 (exact, verified R3/R4).
// Grid (33, BB): blocks 0..31 = 4 wave-jobs each; block 32 = edge v=2048.
__global__ __launch_bounds__(256) void k_dft(const float* __restrict__ x,
                                             const float* __restrict__ T,
                                             float* __restrict__ Xp) {
    const int b = blockIdx.y;
    const int wave = threadIdx.x >> 6, lane = threadIdx.x & 63;

    int vchunk, hh;
    if (blockIdx.x < 32) {
        int job = blockIdx.x * 4 + wave;       // 0..127
        vchunk = job >> 1;                     // 0..63
        hh = job & 1;
    } else {
        if (wave >= 2) return;
        vchunk = 64;
        hh = wave;
    }
    const int h2 = hh * 128 + lane * 2;
    const float* xb = x + (size_t)b * SS * HH + h2;

    float cs[MM][2], sn[MM][2];
#pragma unroll
    for (int k = 0; k < MM; k++) { cs[k][0] = cs[k][1] = 0.f; sn[k][0] = sn[k][1] = 0.f; }

    auto body = [&](int v) {
        float hf = (v == 0 || v == SS / 4) ? 0.5f : 1.0f;
        float2 a0 = *(const float2*)(xb + (size_t)v * HH);
        float2 a1 = *(const float2*)(xb + (size_t)((SS - v) & (SS - 1)) * HH);
        float2 a2 = *(const float2*)(xb + (size_t)(SS / 2 - v) * HH);
        float2 a3 = *(const float2*)(xb + (size_t)(SS / 2 + v) * HH);
        float upw[2], umw[2], dpe[2], dme[2];
        {
            float u = (a0.x + a1.x) * hf, d = (a0.x - a1.x) * hf;
            float w = (a2.x + a3.x) * hf, e = (a3.x - a2.x) * hf;
            upw[0] = u + w; umw[0] = u - w; dpe[0] = d + e; dme[0] = d - e;
        }
        {
            float u = (a0.y + a1.y) * hf, d = (a0.y - a1.y) * hf;
            float w = (a2.y + a3.y) * hf, e = (a3.y - a2.y) * hf;
            upw[1] = u + w; umw[1] = u - w; dpe[1] = d + e; dme[1] = d - e;
        }
        const float4* tw4 = (const float4*)(T + (size_t)v * 32);
#pragma unroll
        for (int j = 0; j < 8; j++) {
            float4 t = tw4[j];
#pragma unroll
            for (int c = 0; c < 2; c++) {
                cs[2 * j][c]     = fmaf(t.x, upw[c], cs[2 * j][c]);
                sn[2 * j][c]     = fmaf(t.y, dpe[c], sn[2 * j][c]);
                cs[2 * j + 1][c] = fmaf(t.z, umw[c], cs[2 * j + 1][c]);
                sn[2 * j + 1][c] = fmaf(t.w, dme[c], sn[2 * j + 1][c]);
            }
        }
    };

    if (vchunk < 64) {
        const int v0 = vchunk * 32;
#pragma unroll 4
        for (int i = 0; i < 32; i++) body(v0 + i);
    } else {
        body(SS / 4);                          // v = 2048
    }

    size_t base = ((size_t)(b * DNC + vchunk) * MM) * (2 * HH) + h2;
#pragma unroll
    for (int k = 0; k < MM; k++) {
        *(float2*)(Xp + base + (size_t)k * (2 * HH))      = make_float2(cs[k][0], cs[k][1]);
        *(float2*)(Xp + base + (size_t)k * (2 * HH) + HH) = make_float2(sn[k][0], sn[k][1]);
    }
}

// Stage 2a: reduce partials over chunks.
__global__ __launch_bounds__(256) void k_reduce(const float* __restrict__ Xp,
                                                float* __restrict__ Xs) {
    const int t = blockIdx.x * 256 + threadIdx.x;
    const int INNER = MM * 2 * HH;                  // 8192
    int idx4 = t * 4;
    int inner = idx4 & (INNER - 1);
    int b = idx4 >> 13;
    const float* src = Xp + ((size_t)b * DNC) * INNER + inner;
    float4 s = make_float4(0.f, 0.f, 0.f, 0.f);
#pragma unroll 5
    for (int p = 0; p < DNC; p++) {
        float4 v = *(const float4*)(src + (size_t)p * INNER);
        s.x += v.x; s.y += v.y; s.z += v.z; s.w += v.w;
    }
    *(float4*)(Xs + idx4) = s;
}

// Stage 2b: complex mix.
__global__ __launch_bounds__(256) void k_mix2(const float* __restrict__ Xs,
                                              const float* __restrict__ Wtr,
                                              const float* __restrict__ Wti,
                                              float* __restrict__ AB) {
    const int m = blockIdx.x, b = blockIdx.y, t = threadIdx.x;
    __shared__ float xr_s[HH], xs_s[HH];
    size_t xbase = (((size_t)b * MM + m) * 2) * HH;
    xr_s[t] = Xs[xbase + t];
    xs_s[t] = Xs[xbase + HH + t];
    __syncthreads();

    const float* wr_m = Wtr + (size_t)m * (HH * HH);
    const float* wi_m = Wti + (size_t)m * (HH * HH);
    float re = 0.f, im = 0.f;
#pragma unroll 8
    for (int h = 0; h < HH; h++) {
        float a  = wr_m[(size_t)h * HH + t];
        float bw = wi_m[(size_t)h * HH + t];
        float xr = xr_s[h];
        float xs = xs_s[h];
        re = fmaf(xr, a, re);  re = fmaf(xs, bw, re);
        im = fmaf(xr, bw, im); im = fmaf(-xs, a, im);
    }
    float scale = (m == 0 ? 1.f : 2.f) / (float)SS;
    size_t o = (((size_t)b * MM + m) * 2) * HH + t;
    AB[o]      = scale * re;
    AB[o + HH] = -scale * im;
}

// Stage 3: folded synthesis + GELU (4 scattered stores per table row).
__global__ __launch_bounds__(256) void k_synth(const float* __restrict__ AB,
                                               const float* __restrict__ T,
                                               float* __restrict__ out) {
    const int c = blockIdx.x, b = blockIdx.y, h = threadIdx.x;
    float a[MM], bc[MM];
#pragma unroll
    for (int k = 0; k < MM; k++) {
        size_t o = (((size_t)b * MM + k) * 2) * HH + h;
        a[k]  = AB[o];
        bc[k] = AB[o + HH];
    }
    const int nv = (c == SNC - 1) ? 1 : SCH;
    const int v0 = c * SCH;
    float* ob = out + (size_t)b * SS * HH + h;

#pragma unroll 2
    for (int i = 0; i < nv; i++) {
        int v = v0 + i;
        const float4* tw4 = (const float4*)(T + (size_t)v * 32);
        float Pe = 0.f, Po = 0.f, Qe = 0.f, Qo = 0.f;
#pragma unroll
        for (int j = 0; j < 8; j++) {
            float4 t = tw4[j];
            Pe = fmaf(a[2 * j],      t.x, Pe);
            Qe = fmaf(bc[2 * j],     t.y, Qe);
            Po = fmaf(a[2 * j + 1],  t.z, Po);
            Qo = fmaf(bc[2 * j + 1], t.w, Qo);
        }
        float Pp = Pe + Po, Pm = Pe - Po, Qp = Qe + Qo, Qm = Qe - Qo;
        ob[(size_t)v * HH]                        = fast_gelu(Pp + Qp);
        ob[(size_t)(SS / 2 - v) * HH]             = fast_gelu(Pm - Qm);
        ob[(size_t)(SS / 2 + v) * HH]             = fast_gelu(Pm + Qm);
        ob[(size_t)((SS - v) & (SS - 1)) * HH]    = fast_gelu(Pp - Qp);
    }
}

extern "C" void kernel_launch(void* const* d_in, const int* in_sizes, int n_in,
                              void* d_out, int out_size, void* d_ws, size_t ws_size,
                              hipStream_t stream) {
    const float* x   = (const float*)d_in[0];
    const float* w_r = (const float*)d_in[1];
    const float* w_i = (const float*)d_in[2];
    float* out = (float*)d_out;
    float* ws  = (float*)d_ws;

    float* T   = ws;
    float* AB  = ws + 262144;
    float* Xs  = ws + 393216;
    float* Xp  = out;                             // 8.5M floats scratch
    float* Wtr = out + (size_t)16 * 1024 * 1024;  // 1M floats scratch
    float* Wti = out + (size_t)17 * 1024 * 1024;  // 1M floats scratch

    hipLaunchKernelGGL(k_twiddle, dim3((NV * MM + 255) / 256), dim3(256), 0, stream, T);
    hipLaunchKernelGGL(k_wt,     dim3(HH, 2), dim3(256), 0, stream, w_r, w_i, Wtr, Wti);
    hipLaunchKernelGGL(k_dft,    dim3(33, BB), dim3(256), 0, stream, x, T, Xp);
    hipLaunchKernelGGL(k_reduce, dim3(BB * MM * 2 * HH / 1024), dim3(256), 0, stream, Xp, Xs);
    hipLaunchKernelGGL(k_mix2,   dim3(MM, BB), dim3(256), 0, stream, Xs, Wtr, Wti, AB);
    hipLaunchKernelGGL(k_synth,  dim3(SNC, BB), dim3(256), 0, stream, AB, T, out);
}

// Round 6
// 116.969 us; speedup vs baseline: 1.0923x; 1.0917x over previous
//
#include <hip/hip_runtime.h>
#include <math.h>

#define BB 16
#define SS 8192
#define HH 256
#define MM 16
#define NV 2049          // folded v range: 0..2048
#define VC 8             // v per staged chunk
#define CPB 4            // chunks per block (block covers 32 v)
#define DNC 65           // partial chunks: 64 main blocks + 1 edge (v=0)
#define SCH 16           // v per k_synth block
#define SNC 129          // k_synth chunks: 128 full + 1 edge

// ws layout (floats): T [NV][32] at 0 (reserve 262144), AB at 262144,
// Xs at 393216.  d_out scratch: Xp [BB][DNC][MM][2][HH] (8.5M floats) at 0,
// Wt_r at 16M floats, Wt_i at 17M floats — all consumed before k_synth writes.

__device__ __forceinline__ void gl_lds16(const float* g, float* l) {
    // async global->LDS, 16B/lane.  LDS dest = wave-uniform base + lane*16.
    __builtin_amdgcn_global_load_lds(
        (const __attribute__((address_space(1))) void*)g,
        (__attribute__((address_space(3))) void*)l, 16, 0, 0);
}

__global__ __launch_bounds__(256) void k_twiddle(float* __restrict__ T) {
    int idx = blockIdx.x * 256 + threadIdx.x;   // 0 .. NV*MM-1
    if (idx >= NV * MM) return;
    int v = idx >> 4, k = idx & 15;
    int r = (k * v) & (SS - 1);                 // exact angle reduction
    float th = (float)r * (6.28318530717958647692f / (float)SS);
    float sn, cn;
    sincosf(th, &sn, &cn);
    T[v * 32 + 2 * k]     = cn;
    T[v * 32 + 2 * k + 1] = sn;
}

// Transpose W: Wt[m][h][k'] = w[h][k'][m].
__global__ __launch_bounds__(256) void k_wt(const float* __restrict__ wr,
                                            const float* __restrict__ wi,
                                            float* __restrict__ Wtr,
                                            float* __restrict__ Wti) {
    __shared__ float lds[4096 + 256];
    const int h = blockIdx.x, t = threadIdx.x;
    const float* src = (blockIdx.y == 0 ? wr : wi) + (size_t)h * 4096;
    float* dst = (blockIdx.y == 0 ? Wtr : Wti);
#pragma unroll
    for (int j = 0; j < 16; j++) {
        int i = j * 256 + t;
        lds[i + (i >> 4)] = src[i];
    }
    __syncthreads();
#pragma unroll
    for (int m = 0; m < 16; m++) {
        int i = t * 16 + m;
        dst[(size_t)m * (HH * HH) + (size_t)h * HH + t] = lds[i + (i >> 4)];
    }
}

// Branchless exact-GELU via A&S 7.1.26 erf (|err| ~ 1.5e-7).
__device__ __forceinline__ float fast_gelu(float y) {
    float x  = fabsf(y) * 0.70710678118654752f;
    float t  = __builtin_amdgcn_rcpf(fmaf(0.3275911f, x, 1.0f));
    float e  = __expf(-x * x);
    float p  = fmaf(fmaf(fmaf(fmaf(1.061405429f, t, -1.453152027f), t,
                   1.421413741f), t, -0.284496736f), t, 0.254829592f) * t;
    float erfabs = fmaf(-p, e, 1.0f);
    return fmaf(0.5f * fabsf(y), erfabs, 0.5f * y);
}

// Stage 1: folded pruned DFT, LDS-staged streaming.
// Block bx<64 handles v = 1+32*bx .. 32*bx+32 as 4 chunks of 8.  Per chunk,
// 4 contiguous 8-row strips {A=[v0..], B=(S/2-v0-7..S/2-v0], C=[S/2+v0..],
// D=(S-v0-7..S-v0]} stream into LDS via global_load_lds (8 x 4KB rounds),
// double-buffered with counted vmcnt(8) + raw s_barrier (loads never drain
// mid-loop).  Fold + 32 twiddle-FMA per v read from LDS (stride-1, no
// conflicts).  v=2048 lands in chunk 255 with hf=0.5 (duplicate rows).
// Block bx==64: edge v=0 (rows 0 and 4096; cos=1, sin=0 for all k).
__global__ __launch_bounds__(256) void k_dft(const float* __restrict__ x,
                                             const float* __restrict__ T,
                                             float* __restrict__ Xp) {
    const int b = blockIdx.y, bx = blockIdx.x, t = threadIdx.x;
    const int w = t >> 6;                        // wave id (uniform per wave)
    const float* xb = x + (size_t)b * SS * HH;

    float cs[MM], sn[MM];
#pragma unroll
    for (int k = 0; k < MM; k++) { cs[k] = 0.f; sn[k] = 0.f; }

    __shared__ float lds[2][4 * VC * HH];        // 2 x 8192 floats = 64 KB

    if (bx == 64) {                              // edge v = 0, hf = 0.5
        float x0 = xb[t];
        float x2 = xb[(size_t)(SS / 2) * HH + t];
#pragma unroll
        for (int j = 0; j < 8; j++) {
            cs[2 * j]     = x0 + x2;             // upw, cos=1
            cs[2 * j + 1] = x0 - x2;             // umw, cos=1
        }                                        // sn = 0 (sin=0, d=e=0)
    } else {
        const int c0 = bx * CPB;

        auto stage = [&](int c, int buf) {
            int v0 = 1 + VC * c;
            const float* bases[4] = {
                xb + (size_t)v0 * HH,
                xb + (size_t)(SS / 2 - v0 - (VC - 1)) * HH,
                xb + (size_t)(SS / 2 + v0) * HH,
                xb + (size_t)(SS - v0 - (VC - 1)) * HH };
#pragma unroll
            for (int s = 0; s < 4; s++)
#pragma unroll
                for (int q = 0; q < 2; q++)
                    gl_lds16(bases[s] + q * 1024 + t * 4,
                             &lds[buf][s * 2048 + q * 1024 + w * 256]);
        };

        auto compute = [&](int c, int buf) {
            int v0 = 1 + VC * c;
            const float* L = &lds[buf][0];
#pragma unroll
            for (int i = 0; i < VC; i++) {
                int v = v0 + i;
                float x0 = L[0 * 2048 + i * 256 + t];            // row v
                float x2 = L[1 * 2048 + (VC - 1 - i) * 256 + t]; // row S/2-v
                float x3 = L[2 * 2048 + i * 256 + t];            // row S/2+v
                float x1 = L[3 * 2048 + (VC - 1 - i) * 256 + t]; // row S-v
                float hf = (v == SS / 4) ? 0.5f : 1.0f;          // v==2048
                float u = (x0 + x1) * hf, d = (x0 - x1) * hf;
                float ww = (x2 + x3) * hf, e = (x3 - x2) * hf;
                float upw = u + ww, umw = u - ww, dpe = d + e, dme = d - e;
                const float4* tw4 = (const float4*)(T + (size_t)v * 32);
#pragma unroll
                for (int j = 0; j < 8; j++) {
                    float4 tt = tw4[j];
                    cs[2 * j]     = fmaf(tt.x, upw, cs[2 * j]);
                    sn[2 * j]     = fmaf(tt.y, dpe, sn[2 * j]);
                    cs[2 * j + 1] = fmaf(tt.z, umw, cs[2 * j + 1]);
                    sn[2 * j + 1] = fmaf(tt.w, dme, sn[2 * j + 1]);
                }
            }
        };

        stage(c0, 0);
        for (int j = 0; j < CPB; j++) {
            if (j < CPB - 1) {
                stage(c0 + j + 1, (j + 1) & 1);  // prefetch next chunk
                asm volatile("s_waitcnt vmcnt(8)" ::: "memory");
            } else {
                asm volatile("s_waitcnt vmcnt(0)" ::: "memory");
            }
            __builtin_amdgcn_sched_barrier(0);
            __builtin_amdgcn_s_barrier();        // chunk j staged for all waves
            compute(c0 + j, j & 1);
            __builtin_amdgcn_s_barrier();        // safe to overwrite buf (j&1)
        }
    }

    size_t base = ((size_t)(b * DNC + bx) * MM) * (2 * HH) + t;
#pragma unroll
    for (int k = 0; k < MM; k++) {
        Xp[base + (size_t)k * (2 * HH)]      = cs[k];
        Xp[base + (size_t)k * (2 * HH) + HH] = sn[k];
    }
}

// Stage 2a: reduce partials over chunks.
__global__ __launch_bounds__(256) void k_reduce(const float* __restrict__ Xp,
                                                float* __restrict__ Xs) {
    const int t = blockIdx.x * 256 + threadIdx.x;
    const int INNER = MM * 2 * HH;                  // 8192
    int idx4 = t * 4;
    int inner = idx4 & (INNER - 1);
    int b = idx4 >> 13;
    const float* src = Xp + ((size_t)b * DNC) * INNER + inner;
    float4 s = make_float4(0.f, 0.f, 0.f, 0.f);
#pragma unroll 5
    for (int p = 0; p < DNC; p++) {
        float4 v = *(const float4*)(src + (size_t)p * INNER);
        s.x += v.x; s.y += v.y; s.z += v.z; s.w += v.w;
    }
    *(float4*)(Xs + idx4) = s;
}

// Stage 2b: complex mix.
__global__ __launch_bounds__(256) void k_mix2(const float* __restrict__ Xs,
                                              const float* __restrict__ Wtr,
                                              const float* __restrict__ Wti,
                                              float* __restrict__ AB) {
    const int m = blockIdx.x, b = blockIdx.y, t = threadIdx.x;
    __shared__ float xr_s[HH], xs_s[HH];
    size_t xbase = (((size_t)b * MM + m) * 2) * HH;
    xr_s[t] = Xs[xbase + t];
    xs_s[t] = Xs[xbase + HH + t];
    __syncthreads();

    const float* wr_m = Wtr + (size_t)m * (HH * HH);
    const float* wi_m = Wti + (size_t)m * (HH * HH);
    float re = 0.f, im = 0.f;
#pragma unroll 8
    for (int h = 0; h < HH; h++) {
        float a  = wr_m[(size_t)h * HH + t];
        float bw = wi_m[(size_t)h * HH + t];
        float xr = xr_s[h];
        float xs = xs_s[h];
        re = fmaf(xr, a, re);  re = fmaf(xs, bw, re);
        im = fmaf(xr, bw, im); im = fmaf(-xs, a, im);
    }
    float scale = (m == 0 ? 1.f : 2.f) / (float)SS;
    size_t o = (((size_t)b * MM + m) * 2) * HH + t;
    AB[o]      = scale * re;
    AB[o + HH] = -scale * im;
}

// Stage 3: folded synthesis + GELU (4 scattered stores per table row).
__global__ __launch_bounds__(256) void k_synth(const float* __restrict__ AB,
                                               const float* __restrict__ T,
                                               float* __restrict__ out) {
    const int c = blockIdx.x, b = blockIdx.y, h = threadIdx.x;
    float a[MM], bc[MM];
#pragma unroll
    for (int k = 0; k < MM; k++) {
        size_t o = (((size_t)b * MM + k) * 2) * HH + h;
        a[k]  = AB[o];
        bc[k] = AB[o + HH];
    }
    const int nv = (c == SNC - 1) ? 1 : SCH;
    const int v0 = c * SCH;
    float* ob = out + (size_t)b * SS * HH + h;

#pragma unroll 2
    for (int i = 0; i < nv; i++) {
        int v = v0 + i;
        const float4* tw4 = (const float4*)(T + (size_t)v * 32);
        float Pe = 0.f, Po = 0.f, Qe = 0.f, Qo = 0.f;
#pragma unroll
        for (int j = 0; j < 8; j++) {
            float4 t = tw4[j];
            Pe = fmaf(a[2 * j],      t.x, Pe);
            Qe = fmaf(bc[2 * j],     t.y, Qe);
            Po = fmaf(a[2 * j + 1],  t.z, Po);
            Qo = fmaf(bc[2 * j + 1], t.w, Qo);
        }
        float Pp = Pe + Po, Pm = Pe - Po, Qp = Qe + Qo, Qm = Qe - Qo;
        ob[(size_t)v * HH]                        = fast_gelu(Pp + Qp);
        ob[(size_t)(SS / 2 - v) * HH]             = fast_gelu(Pm - Qm);
        ob[(size_t)(SS / 2 + v) * HH]             = fast_gelu(Pm + Qm);
        ob[(size_t)((SS - v) & (SS - 1)) * HH]    = fast_gelu(Pp - Qp);
    }
}

extern "C" void kernel_launch(void* const* d_in, const int* in_sizes, int n_in,
                              void* d_out, int out_size, void* d_ws, size_t ws_size,
                              hipStream_t stream) {
    const float* x   = (const float*)d_in[0];
    const float* w_r = (const float*)d_in[1];
    const float* w_i = (const float*)d_in[2];
    float* out = (float*)d_out;
    float* ws  = (float*)d_ws;

    float* T   = ws;
    float* AB  = ws + 262144;
    float* Xs  = ws + 393216;
    float* Xp  = out;                             // 8.5M floats scratch
    float* Wtr = out + (size_t)16 * 1024 * 1024;  // 1M floats scratch
    float* Wti = out + (size_t)17 * 1024 * 1024;  // 1M floats scratch

    hipLaunchKernelGGL(k_twiddle, dim3((NV * MM + 255) / 256), dim3(256), 0, stream, T);
    hipLaunchKernelGGL(k_wt,     dim3(HH, 2), dim3(256), 0, stream, w_r, w_i, Wtr, Wti);
    hipLaunchKernelGGL(k_dft,    dim3(DNC, BB), dim3(256), 0, stream, x, T, Xp);
    hipLaunchKernelGGL(k_reduce, dim3(BB * MM * 2 * HH / 1024), dim3(256), 0, stream, Xp, Xs);
    hipLaunchKernelGGL(k_mix2,   dim3(MM, BB), dim3(256), 0, stream, Xs, Wtr, Wti, AB);
    hipLaunchKernelGGL(k_synth,  dim3(SNC, BB), dim3(256), 0, stream, AB, T, out);
}

// Round 7
// 111.187 us; speedup vs baseline: 1.1491x; 1.0520x over previous
//
#include <hip/hip_runtime.h>
#include <math.h>

#define BB 16
#define SS 8192
#define HH 256
#define MM 16
#define NV 2049          // folded v range: 0..2048
#define VC 4             // v-rows per strip per staged chunk (16 KB chunks)
#define CPB 16           // chunks per main block (64 v per block)
#define DNC 33           // partial chunks: 32 main blocks + 1 edge (v=0)
#define SCH 16           // v per k_synth block
#define SNC 129          // k_synth chunks: 128 full + 1 edge

// ws layout (floats): T [NV][32] at 0 (reserve 262144), AB at 262144.
// d_out scratch: Xp [BB][DNC][MM][2][HH] (4.3M floats, 17.3 MB) at 0,
// Wt_r at 16M floats, Wt_i at 17M floats — all consumed before k_synth writes.

__device__ __forceinline__ void gl_lds16(const float* g, float* l) {
    // async global->LDS, 16B/lane.  LDS dest = wave-uniform base + lane*16.
    __builtin_amdgcn_global_load_lds(
        (const __attribute__((address_space(1))) void*)g,
        (__attribute__((address_space(3))) void*)l, 16, 0, 0);
}

// Fused setup: blocks 0..128 build twiddle table T; blocks 129..640 transpose
// W (Wt[m][h][k'] = w[h][k'][m]) via padded LDS.
__global__ __launch_bounds__(256) void k_pre(const float* __restrict__ wr,
                                             const float* __restrict__ wi,
                                             float* __restrict__ T,
                                             float* __restrict__ Wtr,
                                             float* __restrict__ Wti) {
    const int t = threadIdx.x;
    if (blockIdx.x < 129) {
        int idx = blockIdx.x * 256 + t;         // 0 .. NV*MM-1
        if (idx >= NV * MM) return;
        int v = idx >> 4, k = idx & 15;
        int r = (k * v) & (SS - 1);             // exact angle reduction
        float th = (float)r * (6.28318530717958647692f / (float)SS);
        float sn, cn;
        sincosf(th, &sn, &cn);
        T[v * 32 + 2 * k]     = cn;
        T[v * 32 + 2 * k + 1] = sn;
    } else {
        __shared__ float lds[4096 + 256];
        int bid = blockIdx.x - 129;             // 0..511
        int h = bid & 255, y = bid >> 8;
        const float* src = (y == 0 ? wr : wi) + (size_t)h * 4096;
        float* dst = (y == 0 ? Wtr : Wti);
#pragma unroll
        for (int j = 0; j < 16; j++) {
            int i = j * 256 + t;
            lds[i + (i >> 4)] = src[i];
        }
        __syncthreads();
#pragma unroll
        for (int m = 0; m < 16; m++) {
            int i = t * 16 + m;
            dst[(size_t)m * (HH * HH) + (size_t)h * HH + t] = lds[i + (i >> 4)];
        }
    }
}

// Branchless exact-GELU via A&S 7.1.26 erf (|err| ~ 1.5e-7).
__device__ __forceinline__ float fast_gelu(float y) {
    float x  = fabsf(y) * 0.70710678118654752f;
    float t  = __builtin_amdgcn_rcpf(fmaf(0.3275911f, x, 1.0f));
    float e  = __expf(-x * x);
    float p  = fmaf(fmaf(fmaf(fmaf(1.061405429f, t, -1.453152027f), t,
                   1.421413741f), t, -0.284496736f), t, 0.254829592f) * t;
    float erfabs = fmaf(-p, e, 1.0f);
    return fmaf(0.5f * fabsf(y), erfabs, 0.5f * y);
}

// Stage 1: folded pruned DFT, LDS-staged streaming, triple-buffered with
// prefetch depth 2 (16 KB chunks; 32 KB in flight per block; vmcnt counted,
// never drained mid-loop).  Block bx<32 covers v = 1+64*bx .. 64*bx+64 as 16
// chunks of 4 v; per chunk 4 contiguous 4-row strips {A=[v0..], B=(S/2-v0-3..
// S/2-v0], C=[S/2+v0..], D=(S-v0-3..S-v0]}.  v=2048 lands in the last chunk
// with hf=0.5 (duplicate rows, algebra verified R3-R6).  Block 32: edge v=0.
__global__ __launch_bounds__(256) void k_dft(const float* __restrict__ x,
                                             const float* __restrict__ T,
                                             float* __restrict__ Xp) {
    const int b = blockIdx.y, bx = blockIdx.x, t = threadIdx.x;
    const int w = t >> 6;                        // wave id
    const float* xb = x + (size_t)b * SS * HH;

    float cs[MM], sn[MM];
#pragma unroll
    for (int k = 0; k < MM; k++) { cs[k] = 0.f; sn[k] = 0.f; }

    __shared__ float lds[3][4 * VC * HH];        // 3 x 4096 floats = 48 KB

    if (bx == 32) {                              // edge v = 0
        float x0 = xb[t];
        float x2 = xb[(size_t)(SS / 2) * HH + t];
#pragma unroll
        for (int j = 0; j < 8; j++) {
            cs[2 * j]     = x0 + x2;             // cos=1, even k
            cs[2 * j + 1] = x0 - x2;             // cos=(-1)^k, odd k
        }                                        // sn = 0
    } else {
        const int c0 = bx * CPB;

        auto stage = [&](int c, int buf) {
            int v0 = 1 + VC * c;
            const float* bases[4] = {
                xb + (size_t)v0 * HH,
                xb + (size_t)(SS / 2 - v0 - (VC - 1)) * HH,
                xb + (size_t)(SS / 2 + v0) * HH,
                xb + (size_t)(SS - v0 - (VC - 1)) * HH };
#pragma unroll
            for (int s = 0; s < 4; s++)
                gl_lds16(bases[s] + t * 4, &lds[buf][s * 1024 + w * 256]);
        };

        auto compute = [&](int c, int buf) {
            int v0 = 1 + VC * c;
            const float* L = &lds[buf][0];
#pragma unroll
            for (int i = 0; i < VC; i++) {
                int v = v0 + i;
                float x0 = L[0 * 1024 + i * 256 + t];            // row v
                float x2 = L[1 * 1024 + (VC - 1 - i) * 256 + t]; // row S/2-v
                float x3 = L[2 * 1024 + i * 256 + t];            // row S/2+v
                float x1 = L[3 * 1024 + (VC - 1 - i) * 256 + t]; // row S-v
                float hf = (v == SS / 4) ? 0.5f : 1.0f;          // v==2048
                float u = (x0 + x1) * hf, d = (x0 - x1) * hf;
                float ww = (x2 + x3) * hf, e = (x3 - x2) * hf;
                float upw = u + ww, umw = u - ww, dpe = d + e, dme = d - e;
                const float4* tw4 = (const float4*)(T + (size_t)v * 32);
#pragma unroll
                for (int j = 0; j < 8; j++) {
                    float4 tt = tw4[j];
                    cs[2 * j]     = fmaf(tt.x, upw, cs[2 * j]);
                    sn[2 * j]     = fmaf(tt.y, dpe, sn[2 * j]);
                    cs[2 * j + 1] = fmaf(tt.z, umw, cs[2 * j + 1]);
                    sn[2 * j + 1] = fmaf(tt.w, dme, sn[2 * j + 1]);
                }
            }
        };

        stage(c0, 0);
        stage(c0 + 1, 1);
        for (int j = 0; j < CPB; j++) {
            if (j + 2 < CPB) {
                stage(c0 + j + 2, (j + 2) % 3);  // depth-2 prefetch
                asm volatile("s_waitcnt vmcnt(8)" ::: "memory");   // chunk j done
            } else if (j + 1 < CPB) {
                asm volatile("s_waitcnt vmcnt(4)" ::: "memory");
            } else {
                asm volatile("s_waitcnt vmcnt(0)" ::: "memory");
            }
            __builtin_amdgcn_sched_barrier(0);
            __builtin_amdgcn_s_barrier();        // chunk j staged for all waves
            compute(c0 + j, j % 3);
            __builtin_amdgcn_s_barrier();        // buf reusable for j+3
        }
    }

    size_t base = ((size_t)(b * DNC + bx) * MM) * (2 * HH) + t;
#pragma unroll
    for (int k = 0; k < MM; k++) {
        Xp[base + (size_t)k * (2 * HH)]      = cs[k];
        Xp[base + (size_t)k * (2 * HH) + HH] = sn[k];
    }
}

// Stage 2 (fused reduce+mix): block (m,b).  Phase A: sum Xp over 33 partials
// (coalesced 1KB strips, 4-deep unrolled independent loads) into LDS.
// Phase B: X = cs - i*sn;  O[k'] = sum_h X[h]*(wr+i*wi)[h,k',m];
// A = scale*Re(O), Bc = -scale*Im(O), scale = (m==0?1:2)/SS.
__global__ __launch_bounds__(256) void k_mix(const float* __restrict__ Xp,
                                             const float* __restrict__ Wtr,
                                             const float* __restrict__ Wti,
                                             float* __restrict__ AB) {
    const int m = blockIdx.x, b = blockIdx.y, t = threadIdx.x;
    __shared__ float xr_s[HH], xs_s[HH];

    float s0 = 0.f, s1 = 0.f;
    size_t base = (((size_t)b * DNC) * MM + m) * (2 * HH) + t;
    const size_t pstride = (size_t)MM * 2 * HH;
#pragma unroll 4
    for (int p = 0; p < DNC; p++) {
        s0 += Xp[base + (size_t)p * pstride];
        s1 += Xp[base + (size_t)p * pstride + HH];
    }
    xr_s[t] = s0;
    xs_s[t] = s1;
    __syncthreads();

    const float* wr_m = Wtr + (size_t)m * (HH * HH);
    const float* wi_m = Wti + (size_t)m * (HH * HH);
    float re = 0.f, im = 0.f;
#pragma unroll 8
    for (int h = 0; h < HH; h++) {
        float a  = wr_m[(size_t)h * HH + t];    // lane-contiguous, 1KB/wave
        float bw = wi_m[(size_t)h * HH + t];
        float xr = xr_s[h];                     // LDS broadcast
        float xs = xs_s[h];
        re = fmaf(xr, a, re);  re = fmaf(xs, bw, re);
        im = fmaf(xr, bw, im); im = fmaf(-xs, a, im);
    }
    float scale = (m == 0 ? 1.f : 2.f) / (float)SS;
    size_t o = (((size_t)b * MM + m) * 2) * HH + t;
    AB[o]      = scale * re;
    AB[o + HH] = -scale * im;
}

// Stage 3: folded synthesis + GELU (4 scattered stores per table row).
__global__ __launch_bounds__(256) void k_synth(const float* __restrict__ AB,
                                               const float* __restrict__ T,
                                               float* __restrict__ out) {
    const int c = blockIdx.x, b = blockIdx.y, h = threadIdx.x;
    float a[MM], bc[MM];
#pragma unroll
    for (int k = 0; k < MM; k++) {
        size_t o = (((size_t)b * MM + k) * 2) * HH + h;
        a[k]  = AB[o];
        bc[k] = AB[o + HH];
    }
    const int nv = (c == SNC - 1) ? 1 : SCH;
    const int v0 = c * SCH;
    float* ob = out + (size_t)b * SS * HH + h;

#pragma unroll 2
    for (int i = 0; i < nv; i++) {
        int v = v0 + i;
        const float4* tw4 = (const float4*)(T + (size_t)v * 32);
        float Pe = 0.f, Po = 0.f, Qe = 0.f, Qo = 0.f;
#pragma unroll
        for (int j = 0; j < 8; j++) {
            float4 t = tw4[j];
            Pe = fmaf(a[2 * j],      t.x, Pe);
            Qe = fmaf(bc[2 * j],     t.y, Qe);
            Po = fmaf(a[2 * j + 1],  t.z, Po);
            Qo = fmaf(bc[2 * j + 1], t.w, Qo);
        }
        float Pp = Pe + Po, Pm = Pe - Po, Qp = Qe + Qo, Qm = Qe - Qo;
        ob[(size_t)v * HH]                        = fast_gelu(Pp + Qp);
        ob[(size_t)(SS / 2 - v) * HH]             = fast_gelu(Pm - Qm);
        ob[(size_t)(SS / 2 + v) * HH]             = fast_gelu(Pm + Qm);
        ob[(size_t)((SS - v) & (SS - 1)) * HH]    = fast_gelu(Pp - Qp);
    }
}

extern "C" void kernel_launch(void* const* d_in, const int* in_sizes, int n_in,
                              void* d_out, int out_size, void* d_ws, size_t ws_size,
                              hipStream_t stream) {
    const float* x   = (const float*)d_in[0];
    const float* w_r = (const float*)d_in[1];
    const float* w_i = (const float*)d_in[2];
    float* out = (float*)d_out;
    float* ws  = (float*)d_ws;

    float* T   = ws;
    float* AB  = ws + 262144;
    float* Xp  = out;                             // 4.3M floats scratch
    float* Wtr = out + (size_t)16 * 1024 * 1024;  // 1M floats scratch
    float* Wti = out + (size_t)17 * 1024 * 1024;  // 1M floats scratch

    hipLaunchKernelGGL(k_pre,   dim3(641), dim3(256), 0, stream, w_r, w_i, T, Wtr, Wti);
    hipLaunchKernelGGL(k_dft,   dim3(DNC, BB), dim3(256), 0, stream, x, T, Xp);
    hipLaunchKernelGGL(k_mix,   dim3(MM, BB), dim3(256), 0, stream, Xp, Wtr, Wti, AB);
    hipLaunchKernelGGL(k_synth, dim3(SNC, BB), dim3(256), 0, stream, AB, T, out);
}